// Round 5
// baseline (311.921 us; speedup 1.0000x reference)
//
#include <hip/hip_runtime.h>
#include <cstdint>
#include <cstddef>

// DenseGAT, N=4096, IN_DIM=256, H=4, D=64, NEG_SLOPE=0.2
// w[i,j,h] = eb * max(t5, tt);  tt = ui*uj = exp(.2(ei+ej)),
//   t5 = ui5*uj5 = exp(ei+ej) = tt^5 (exact), eb = exp(bias) or 0 (masked).
// Row sums via extra MFMA vs ones-B. Partials over j-chunks -> reduce.

typedef _Float16 f16x4 __attribute__((ext_vector_type(4)));
typedef _Float16 f16x8 __attribute__((ext_vector_type(8)));
typedef float f32x4 __attribute__((ext_vector_type(4)));

#define NN 4096

// ---- Kernel 1: Wh = h @ W (fp32) + Vt (fp16 transpose) + ui/uj exps ------
__global__ __launch_bounds__(256) void gemm_wh(
    const float* __restrict__ A, const float* __restrict__ Bw,
    const float* __restrict__ av, float* __restrict__ C,
    _Float16* __restrict__ Vt,
    _Float16* __restrict__ uit, _Float16* __restrict__ ui5t,
    _Float16* __restrict__ ujt, _Float16* __restrict__ uj5t) {
  __shared__ float sA[32][36];
  __shared__ float sB[32][68];
  __shared__ _Float16 sT[64][40];
  const int h  = blockIdx.x;
  const int by = blockIdx.y;
  const int t  = threadIdx.x;
  const int row0 = by * 32, col0 = h * 64;
  const int tc = t & 15, tr = t >> 4;
  float acc[2][4];
  #pragma unroll
  for (int q = 0; q < 2; q++)
    #pragma unroll
    for (int p = 0; p < 4; p++) acc[q][p] = 0.f;

  for (int k0 = 0; k0 < 256; k0 += 32) {
    __syncthreads();
    {
      const int r = t >> 3, k4 = (t & 7) * 4;
      float4 v = *(const float4*)&A[(size_t)(row0 + r) * 256 + k0 + k4];
      sA[k4 + 0][r] = v.x; sA[k4 + 1][r] = v.y;
      sA[k4 + 2][r] = v.z; sA[k4 + 3][r] = v.w;
    }
    #pragma unroll
    for (int q = 0; q < 2; q++) {
      const int u = t + q * 256;
      const int kr = u >> 4, c4 = (u & 15) * 4;
      *(float4*)&sB[kr][c4] =
          *(const float4*)&Bw[(size_t)(k0 + kr) * 256 + col0 + c4];
    }
    __syncthreads();
    #pragma unroll
    for (int kk = 0; kk < 32; kk++) {
      float2 a2 = *(const float2*)&sA[kk][tr * 2];
      float4 bv = *(const float4*)&sB[kk][tc * 4];
      const float bp[4] = {bv.x, bv.y, bv.z, bv.w};
      #pragma unroll
      for (int p = 0; p < 4; p++) {
        acc[0][p] = fmaf(a2.x, bp[p], acc[0][p]);
        acc[1][p] = fmaf(a2.y, bp[p], acc[1][p]);
      }
    }
  }
  #pragma unroll
  for (int q = 0; q < 2; q++) {
    float4 v = make_float4(acc[q][0], acc[q][1], acc[q][2], acc[q][3]);
    *(float4*)&C[(size_t)(row0 + tr * 2 + q) * 256 + col0 + tc * 4] = v;
  }
  {
    float pi[2] = {0.f, 0.f}, pj[2] = {0.f, 0.f};
    #pragma unroll
    for (int q = 0; q < 2; q++)
      #pragma unroll
      for (int p = 0; p < 4; p++) {
        const int d = tc * 4 + p;
        pi[q] = fmaf(acc[q][p], av[h * 128 + d], pi[q]);
        pj[q] = fmaf(acc[q][p], av[h * 128 + 64 + d], pj[q]);
      }
    #pragma unroll
    for (int m = 1; m <= 8; m <<= 1) {
      #pragma unroll
      for (int q = 0; q < 2; q++) {
        pi[q] += __shfl_xor(pi[q], m, 64);
        pj[q] += __shfl_xor(pj[q], m, 64);
      }
    }
    if (tc == 0) {
      #pragma unroll
      for (int q = 0; q < 2; q++) {
        const int row = row0 + tr * 2 + q;
        uit [(size_t)h * NN + row] = (_Float16)__expf(0.2f * pi[q]);
        ui5t[(size_t)h * NN + row] = (_Float16)__expf(pi[q]);
        ujt [(size_t)h * NN + row] = (_Float16)__expf(0.2f * pj[q]);
        uj5t[(size_t)h * NN + row] = (_Float16)__expf(pj[q]);
      }
    }
  }
  #pragma unroll
  for (int q = 0; q < 2; q++)
    #pragma unroll
    for (int p = 0; p < 4; p++)
      sT[tc * 4 + p][tr * 2 + q] = (_Float16)acc[q][p];
  __syncthreads();
  {
    const int dd = t >> 2, j8 = (t & 3) * 8;
    f16x8 w;
    #pragma unroll
    for (int k = 0; k < 8; k++) w[k] = sT[dd][j8 + k];
    *(f16x8*)&Vt[(size_t)(col0 + dd) * NN + row0 + j8] = w;
  }
}

// ---- Kernel 2: fused masked-softmax attention (MFMA) ---------------------
// grid (256 i-tiles of 16, CH j-chunks) = 2048 blocks, 8 blocks/CU.
// block 256 = 4 waves (wave = head). Wave: C[16i x 64d] + ones-col.
__global__ __launch_bounds__(256, 8) void gat_attn(
    const float* __restrict__ bias, const _Float16* __restrict__ Vt,
    const _Float16* __restrict__ uit, const _Float16* __restrict__ ui5t,
    const _Float16* __restrict__ ujt, const _Float16* __restrict__ uj5t,
    float* __restrict__ P, float* __restrict__ L, int jpc) {
  __shared__ _Float16 seb[2][16][136];   // exp(bias) tile [i][j], pad 8
  const int itile = blockIdx.x;
  const int chunk = blockIdx.y;
  const int tid = threadIdx.x;
  const int lane = tid & 63;
  const int h = __builtin_amdgcn_readfirstlane(tid >> 6);
  const int m = lane & 15;
  const int quad = lane >> 4;
  const int i0 = itile * 16;
  const int j0 = chunk * jpc;
  const int nc = jpc >> 7;

  f32x4 acc[5];                          // dt0..3 + ones-col
  #pragma unroll
  for (int dt = 0; dt < 5; dt++)
    #pragma unroll
    for (int r = 0; r < 4; r++) acc[dt][r] = 0.f;

  const _Float16 ui_0 = uit [(size_t)h * NN + i0 + m];
  const _Float16 u5_0 = ui5t[(size_t)h * NN + i0 + m];
  const f16x8 ui8 = {ui_0, ui_0, ui_0, ui_0, ui_0, ui_0, ui_0, ui_0};
  const f16x8 u58 = {u5_0, u5_0, u5_0, u5_0, u5_0, u5_0, u5_0, u5_0};
  const f16x8 kOne = {(_Float16)1.f, (_Float16)1.f, (_Float16)1.f, (_Float16)1.f,
                      (_Float16)1.f, (_Float16)1.f, (_Float16)1.f, (_Float16)1.f};

  // stage one 16x128 exp(bias) tile; 2 float4 loads/thread
  auto stage = [&](int jc, int buf) {
    const int r = tid >> 4, c8 = (tid & 15) * 8;
    const float* bp = bias + (size_t)(i0 + r) * NN + j0 + jc * 128 + c8;
    float4 v0 = *(const float4*)(bp);
    float4 v1 = *(const float4*)(bp + 4);
    f16x8 e;
    e[0] = (_Float16)((v0.x == 0.f) ? 0.f : __expf(v0.x));
    e[1] = (_Float16)((v0.y == 0.f) ? 0.f : __expf(v0.y));
    e[2] = (_Float16)((v0.z == 0.f) ? 0.f : __expf(v0.z));
    e[3] = (_Float16)((v0.w == 0.f) ? 0.f : __expf(v0.w));
    e[4] = (_Float16)((v1.x == 0.f) ? 0.f : __expf(v1.x));
    e[5] = (_Float16)((v1.y == 0.f) ? 0.f : __expf(v1.y));
    e[6] = (_Float16)((v1.z == 0.f) ? 0.f : __expf(v1.z));
    e[7] = (_Float16)((v1.w == 0.f) ? 0.f : __expf(v1.w));
    *(f16x8*)&seb[buf][r][c8] = e;
  };

  stage(0, 0);
  for (int jc = 0; jc < nc; jc++) {
    const int buf = jc & 1;
    __syncthreads();
    if (jc + 1 < nc) stage(jc + 1, buf ^ 1);

    const _Float16* vb  = Vt + (size_t)(h * 64 + m) * NN + j0 + jc * 128 + quad * 8;
    const _Float16* ujb = ujt  + (size_t)h * NN + j0 + jc * 128 + quad * 8;
    const _Float16* u5b = uj5t + (size_t)h * NN + j0 + jc * 128 + quad * 8;

    f16x8 bc[4], bn[4];
    #pragma unroll
    for (int dt = 0; dt < 4; dt++)
      bc[dt] = *(const f16x8*)(vb + (size_t)(dt * 16) * NN);

    #pragma unroll
    for (int s = 0; s < 4; s++) {
      if (s < 3) {
        #pragma unroll
        for (int dt = 0; dt < 4; dt++)
          bn[dt] = *(const f16x8*)(vb + (size_t)(dt * 16) * NN + (s + 1) * 32);
      }
      const f16x8 uj8  = *(const f16x8*)(ujb + s * 32);
      const f16x8 uj58 = *(const f16x8*)(u5b + s * 32);
      const f16x8 e0 = *(const f16x8*)&seb[buf][m][s * 32 + quad * 8];
      // w = eb * max(ui5*uj5, ui*uj)
      const f16x8 a0 = e0 * __builtin_elementwise_max(u58 * uj58, ui8 * uj8);
      #pragma unroll
      for (int dt = 0; dt < 4; dt++)
        acc[dt] = __builtin_amdgcn_mfma_f32_16x16x32_f16(a0, bc[dt], acc[dt], 0, 0, 0);
      acc[4] = __builtin_amdgcn_mfma_f32_16x16x32_f16(a0, kOne, acc[4], 0, 0, 0);
      if (s < 3) {
        #pragma unroll
        for (int dt = 0; dt < 4; dt++) bc[dt] = bn[dt];
      }
    }
  }

  // epilogue
  const size_t lb = (size_t)(chunk * 4 + h) * NN + i0;
  if (m == 0) {
    #pragma unroll
    for (int r = 0; r < 4; r++) L[lb + quad * 4 + r] = acc[4][r];
  }
  const size_t pbase = ((size_t)(chunk * 4 + h) * NN + i0) * 64;
  #pragma unroll
  for (int dt = 0; dt < 4; dt++)
    #pragma unroll
    for (int r = 0; r < 4; r++)
      P[pbase + (size_t)(quad * 4 + r) * 64 + dt * 16 + m] = acc[dt][r];
}

// ---- Kernel 3: reduce partials, normalize, ELU ---------------------------
template <int CHT>
__global__ __launch_bounds__(256) void reduce_out(
    const float* __restrict__ P, const float* __restrict__ L,
    const float* __restrict__ Wh, float* __restrict__ out) {
  const int i0 = blockIdx.x * 16;
  const int h = blockIdx.y;
  const int t = threadIdx.x;
  const int d = t & 63;
  const int isub = t >> 6;
  #pragma unroll
  for (int ii = 0; ii < 4; ii++) {
    const int i = i0 + isub * 4 + ii;
    float lsum = 0.f, s = 0.f;
    #pragma unroll
    for (int c = 0; c < CHT; c++) {
      lsum += L[(size_t)(c * 4 + h) * NN + i];
      s += P[((size_t)(c * 4 + h) * NN + i) * 64 + d];
    }
    const float wh = Wh[(size_t)i * 256 + h * 64 + d];
    const bool fb = (lsum == 0.f);
    float o = fb ? wh : s / lsum;
    o = (o > 0.f) ? o : (__expf(o) - 1.f);
    out[(size_t)i * 256 + h * 64 + d] = o;
  }
}

extern "C" void kernel_launch(void* const* d_in, const int* in_sizes, int n_in,
                              void* d_out, int out_size, void* d_ws, size_t ws_size,
                              hipStream_t stream) {
  const float* h_in = (const float*)d_in[0];
  const float* adj  = (const float*)d_in[1];
  const float* W    = (const float*)d_in[2];
  const float* a    = (const float*)d_in[3];
  float* out = (float*)d_out;
  float* ws = (float*)d_ws;

  int CH = 8;
  while (CH > 1) {
    size_t floats = 1048576 + 524288 + 32768 + (size_t)CH * (16384 + 1048576);
    if (floats * 4 <= ws_size) break;
    CH >>= 1;
  }
  const int jpc = NN / CH;

  float* Wh = ws;
  _Float16* Vt   = (_Float16*)(ws + 1048576);
  _Float16* uit  = (_Float16*)(ws + 1048576 + 524288);
  _Float16* ui5t = uit + 16384;
  _Float16* ujt  = ui5t + 16384;
  _Float16* uj5t = ujt + 16384;
  float* Lb = ws + 1048576 + 524288 + 32768;
  float* Pb = Lb + (size_t)CH * 16384;

  hipLaunchKernelGGL(gemm_wh, dim3(4, 128), dim3(256), 0, stream,
                     h_in, W, a, Wh, Vt, uit, ui5t, ujt, uj5t);
  hipLaunchKernelGGL(gat_attn, dim3(256, CH), dim3(256), 0, stream,
                     adj, Vt, uit, ui5t, ujt, uj5t, Pb, Lb, jpc);
  switch (CH) {
    case 8: hipLaunchKernelGGL((reduce_out<8>), dim3(256, 4), dim3(256), 0, stream, Pb, Lb, Wh, out); break;
    case 4: hipLaunchKernelGGL((reduce_out<4>), dim3(256, 4), dim3(256), 0, stream, Pb, Lb, Wh, out); break;
    case 2: hipLaunchKernelGGL((reduce_out<2>), dim3(256, 4), dim3(256), 0, stream, Pb, Lb, Wh, out); break;
    default: hipLaunchKernelGGL((reduce_out<1>), dim3(256, 4), dim3(256), 0, stream, Pb, Lb, Wh, out); break;
  }
}

// Round 6
// 183.303 us; speedup vs baseline: 1.7017x; 1.7017x over previous
//
#include <hip/hip_runtime.h>
#include <cstdint>
#include <cstddef>

// DenseGAT, N=4096, IN_DIM=256, H=4, D=64, NEG_SLOPE=0.2
// w[i,j,h] = eb * max(t5, tt);  tt = ui*uj = exp(.2(ei+ej)),
//   t5 = ui5*uj5 = exp(ei+ej) = tt^5 (exact), eb = exp(bias) or 0 (masked).
// R6: no j-chunk partials (R5 showed 268MB P-traffic thrashing L3 -> HBM).
// One 1024-thread block per i-tile of 16 rows: 16 waves = 4 heads x 4
// j-quarters, full softmax in-block, direct output write.

typedef _Float16 f16x4 __attribute__((ext_vector_type(4)));
typedef _Float16 f16x8 __attribute__((ext_vector_type(8)));
typedef float f32x4 __attribute__((ext_vector_type(4)));

#define NN 4096

// ---- Kernel 1: Wh = h @ W (fp32) + Vt (fp16 transpose) + ui/uj exps ------
__global__ __launch_bounds__(256) void gemm_wh(
    const float* __restrict__ A, const float* __restrict__ Bw,
    const float* __restrict__ av, float* __restrict__ C,
    _Float16* __restrict__ Vt,
    _Float16* __restrict__ uit, _Float16* __restrict__ ui5t,
    _Float16* __restrict__ ujt, _Float16* __restrict__ uj5t) {
  __shared__ float sA[32][36];
  __shared__ float sB[32][68];
  __shared__ _Float16 sT[64][40];
  const int h  = blockIdx.x;
  const int by = blockIdx.y;
  const int t  = threadIdx.x;
  const int row0 = by * 32, col0 = h * 64;
  const int tc = t & 15, tr = t >> 4;
  float acc[2][4];
  #pragma unroll
  for (int q = 0; q < 2; q++)
    #pragma unroll
    for (int p = 0; p < 4; p++) acc[q][p] = 0.f;

  for (int k0 = 0; k0 < 256; k0 += 32) {
    __syncthreads();
    {
      const int r = t >> 3, k4 = (t & 7) * 4;
      float4 v = *(const float4*)&A[(size_t)(row0 + r) * 256 + k0 + k4];
      sA[k4 + 0][r] = v.x; sA[k4 + 1][r] = v.y;
      sA[k4 + 2][r] = v.z; sA[k4 + 3][r] = v.w;
    }
    #pragma unroll
    for (int q = 0; q < 2; q++) {
      const int u = t + q * 256;
      const int kr = u >> 4, c4 = (u & 15) * 4;
      *(float4*)&sB[kr][c4] =
          *(const float4*)&Bw[(size_t)(k0 + kr) * 256 + col0 + c4];
    }
    __syncthreads();
    #pragma unroll
    for (int kk = 0; kk < 32; kk++) {
      float2 a2 = *(const float2*)&sA[kk][tr * 2];
      float4 bv = *(const float4*)&sB[kk][tc * 4];
      const float bp[4] = {bv.x, bv.y, bv.z, bv.w};
      #pragma unroll
      for (int p = 0; p < 4; p++) {
        acc[0][p] = fmaf(a2.x, bp[p], acc[0][p]);
        acc[1][p] = fmaf(a2.y, bp[p], acc[1][p]);
      }
    }
  }
  #pragma unroll
  for (int q = 0; q < 2; q++) {
    float4 v = make_float4(acc[q][0], acc[q][1], acc[q][2], acc[q][3]);
    *(float4*)&C[(size_t)(row0 + tr * 2 + q) * 256 + col0 + tc * 4] = v;
  }
  {
    float pi[2] = {0.f, 0.f}, pj[2] = {0.f, 0.f};
    #pragma unroll
    for (int q = 0; q < 2; q++)
      #pragma unroll
      for (int p = 0; p < 4; p++) {
        const int d = tc * 4 + p;
        pi[q] = fmaf(acc[q][p], av[h * 128 + d], pi[q]);
        pj[q] = fmaf(acc[q][p], av[h * 128 + 64 + d], pj[q]);
      }
    #pragma unroll
    for (int m = 1; m <= 8; m <<= 1) {
      #pragma unroll
      for (int q = 0; q < 2; q++) {
        pi[q] += __shfl_xor(pi[q], m, 64);
        pj[q] += __shfl_xor(pj[q], m, 64);
      }
    }
    if (tc == 0) {
      #pragma unroll
      for (int q = 0; q < 2; q++) {
        const int row = row0 + tr * 2 + q;
        uit [(size_t)h * NN + row] = (_Float16)__expf(0.2f * pi[q]);
        ui5t[(size_t)h * NN + row] = (_Float16)__expf(pi[q]);
        ujt [(size_t)h * NN + row] = (_Float16)__expf(0.2f * pj[q]);
        uj5t[(size_t)h * NN + row] = (_Float16)__expf(pj[q]);
      }
    }
  }
  #pragma unroll
  for (int q = 0; q < 2; q++)
    #pragma unroll
    for (int p = 0; p < 4; p++)
      sT[tc * 4 + p][tr * 2 + q] = (_Float16)acc[q][p];
  __syncthreads();
  {
    const int dd = t >> 2, j8 = (t & 3) * 8;
    f16x8 w;
    #pragma unroll
    for (int k = 0; k < 8; k++) w[k] = sT[dd][j8 + k];
    *(f16x8*)&Vt[(size_t)(col0 + dd) * NN + row0 + j8] = w;
  }
}

// ---- Kernel 2: fused attention, full softmax per block -------------------
// grid 256 (i-tiles of 16), block 1024 = 16 waves: head = w>>2, quarter = w&3.
__global__ __launch_bounds__(1024, 4) void gat_attn(
    const float* __restrict__ bias, const _Float16* __restrict__ Vt,
    const _Float16* __restrict__ uit, const _Float16* __restrict__ ui5t,
    const _Float16* __restrict__ ujt, const _Float16* __restrict__ uj5t,
    const float* __restrict__ Wh, float* __restrict__ out) {
  __shared__ __align__(16) char smem[33536];
  _Float16 (*seb)[16][524] = reinterpret_cast<_Float16 (*)[16][524]>(smem);
  float* cmb = reinterpret_cast<float*>(smem);          // [4][2][16][64] lane-major
  float* cl  = reinterpret_cast<float*>(smem + 32768);  // [4][2][16]

  const int tid = threadIdx.x;
  const int lane = tid & 63;
  const int w = tid >> 6;                               // 0..15
  const int head = __builtin_amdgcn_readfirstlane(w >> 2);
  const int q    = __builtin_amdgcn_readfirstlane(w & 3);
  const int m = lane & 15;
  const int quad = lane >> 4;
  const int i0 = blockIdx.x * 16;

  f32x4 acc[5];                          // dt0..3 + ones-col (rowsum)
  #pragma unroll
  for (int dt = 0; dt < 5; dt++)
    #pragma unroll
    for (int r = 0; r < 4; r++) acc[dt][r] = 0.f;

  const _Float16 ui_0 = uit [(size_t)head * NN + i0 + m];
  const _Float16 u5_0 = ui5t[(size_t)head * NN + i0 + m];
  const f16x8 ui8 = {ui_0, ui_0, ui_0, ui_0, ui_0, ui_0, ui_0, ui_0};
  const f16x8 u58 = {u5_0, u5_0, u5_0, u5_0, u5_0, u5_0, u5_0, u5_0};
  const f16x8 kOne = {(_Float16)1.f, (_Float16)1.f, (_Float16)1.f, (_Float16)1.f,
                      (_Float16)1.f, (_Float16)1.f, (_Float16)1.f, (_Float16)1.f};

  // stage: wave w loads bias row (i0+w), 512 cols, exp -> f16 LDS
  auto stage = [&](int jc, int buf) {
    const float* bp = bias + (size_t)(i0 + w) * NN + jc * 512 + lane * 8;
    float4 v0 = *(const float4*)(bp);
    float4 v1 = *(const float4*)(bp + 4);
    f16x8 e;
    e[0] = (_Float16)((v0.x == 0.f) ? 0.f : __expf(v0.x));
    e[1] = (_Float16)((v0.y == 0.f) ? 0.f : __expf(v0.y));
    e[2] = (_Float16)((v0.z == 0.f) ? 0.f : __expf(v0.z));
    e[3] = (_Float16)((v0.w == 0.f) ? 0.f : __expf(v0.w));
    e[4] = (_Float16)((v1.x == 0.f) ? 0.f : __expf(v1.x));
    e[5] = (_Float16)((v1.y == 0.f) ? 0.f : __expf(v1.y));
    e[6] = (_Float16)((v1.z == 0.f) ? 0.f : __expf(v1.z));
    e[7] = (_Float16)((v1.w == 0.f) ? 0.f : __expf(v1.w));
    *(f16x8*)&seb[buf][w][lane * 8] = e;
  };

  stage(0, 0);
  for (int jc = 0; jc < 8; jc++) {
    const int buf = jc & 1;
    __syncthreads();
    if (jc < 7) stage(jc + 1, buf ^ 1);

    const int jb = jc * 512 + q * 128;
    const _Float16* vb  = Vt  + (size_t)(head * 64 + m) * NN + jb + quad * 8;
    const _Float16* ujb = ujt  + (size_t)head * NN + jb + quad * 8;
    const _Float16* u5b = uj5t + (size_t)head * NN + jb + quad * 8;

    f16x8 bc[4], bn[4];
    #pragma unroll
    for (int dt = 0; dt < 4; dt++)
      bc[dt] = *(const f16x8*)(vb + (size_t)(dt * 16) * NN);

    #pragma unroll
    for (int s = 0; s < 4; s++) {
      if (s < 3) {
        #pragma unroll
        for (int dt = 0; dt < 4; dt++)
          bn[dt] = *(const f16x8*)(vb + (size_t)(dt * 16) * NN + (s + 1) * 32);
      }
      const f16x8 uj8  = *(const f16x8*)(ujb + s * 32);
      const f16x8 uj58 = *(const f16x8*)(u5b + s * 32);
      const f16x8 e0 = *(const f16x8*)&seb[buf][m][q * 128 + s * 32 + quad * 8];
      const f16x8 a0 = e0 * __builtin_elementwise_max(u58 * uj58, ui8 * uj8);
      #pragma unroll
      for (int dt = 0; dt < 4; dt++)
        acc[dt] = __builtin_amdgcn_mfma_f32_16x16x32_f16(a0, bc[dt], acc[dt], 0, 0, 0);
      acc[4] = __builtin_amdgcn_mfma_f32_16x16x32_f16(a0, kOne, acc[4], 0, 0, 0);
      if (s < 3) {
        #pragma unroll
        for (int dt = 0; dt < 4; dt++) bc[dt] = bn[dt];
      }
    }
  }
  __syncthreads();   // protect seb before aliasing it as cmb

  // ---- tree-combine the 4 j-quarters per head (lane-major, conflict-free)
  // cmb slot(e, pair): cmb[((head*2+pair)*16 + e)*64 + lane], e = dt*4+r
  const int pair = q >> 1;
  if (q & 1) {
    #pragma unroll
    for (int dt = 0; dt < 4; dt++)
      #pragma unroll
      for (int r = 0; r < 4; r++)
        cmb[((head * 2 + pair) * 16 + dt * 4 + r) * 64 + lane] = acc[dt][r];
    if (m == 0) {
      #pragma unroll
      for (int r = 0; r < 4; r++)
        cl[(head * 2 + pair) * 16 + quad * 4 + r] = acc[4][r];
    }
  }
  __syncthreads();
  if (!(q & 1)) {
    #pragma unroll
    for (int dt = 0; dt < 4; dt++)
      #pragma unroll
      for (int r = 0; r < 4; r++)
        acc[dt][r] += cmb[((head * 2 + pair) * 16 + dt * 4 + r) * 64 + lane];
    #pragma unroll
    for (int r = 0; r < 4; r++)
      acc[4][r] += cl[(head * 2 + pair) * 16 + quad * 4 + r];
  }
  __syncthreads();
  if (q == 2) {
    #pragma unroll
    for (int dt = 0; dt < 4; dt++)
      #pragma unroll
      for (int r = 0; r < 4; r++)
        cmb[((head * 2 + 1) * 16 + dt * 4 + r) * 64 + lane] = acc[dt][r];
    if (m == 0) {
      #pragma unroll
      for (int r = 0; r < 4; r++)
        cl[(head * 2 + 1) * 16 + quad * 4 + r] = acc[4][r];
    }
  }
  __syncthreads();
  if (q == 0) {
    #pragma unroll
    for (int dt = 0; dt < 4; dt++)
      #pragma unroll
      for (int r = 0; r < 4; r++)
        acc[dt][r] += cmb[((head * 2 + 1) * 16 + dt * 4 + r) * 64 + lane];
    #pragma unroll
    for (int r = 0; r < 4; r++)
      acc[4][r] += cl[(head * 2 + 1) * 16 + quad * 4 + r];

    // normalize + ELU + store
    #pragma unroll
    for (int r = 0; r < 4; r++) {
      const int i = i0 + quad * 4 + r;
      const float l = acc[4][r];
      const bool fb = (l == 0.f);
      const float inv = fb ? 0.f : 1.f / l;
      #pragma unroll
      for (int dt = 0; dt < 4; dt++) {
        const int d = dt * 16 + m;
        float o = fb ? Wh[(size_t)i * 256 + head * 64 + d] : acc[dt][r] * inv;
        o = (o > 0.f) ? o : (__expf(o) - 1.f);
        out[(size_t)i * 256 + head * 64 + d] = o;
      }
    }
  }
}

extern "C" void kernel_launch(void* const* d_in, const int* in_sizes, int n_in,
                              void* d_out, int out_size, void* d_ws, size_t ws_size,
                              hipStream_t stream) {
  const float* h_in = (const float*)d_in[0];
  const float* adj  = (const float*)d_in[1];
  const float* W    = (const float*)d_in[2];
  const float* a    = (const float*)d_in[3];
  float* out = (float*)d_out;
  float* ws = (float*)d_ws;

  float* Wh = ws;
  _Float16* Vt   = (_Float16*)(ws + 1048576);
  _Float16* uit  = (_Float16*)(ws + 1048576 + 524288);
  _Float16* ui5t = uit + 16384;
  _Float16* ujt  = ui5t + 16384;
  _Float16* uj5t = ujt + 16384;

  hipLaunchKernelGGL(gemm_wh, dim3(4, 128), dim3(256), 0, stream,
                     h_in, W, a, Wh, Vt, uit, ui5t, ujt, uj5t);
  hipLaunchKernelGGL(gat_attn, dim3(256), dim3(1024), 0, stream,
                     adj, Vt, uit, ui5t, ujt, uj5t, Wh, out);
}